// Round 3
// baseline (1506.306 us; speedup 1.0000x reference)
//
#include <hip/hip_runtime.h>

typedef __bf16 bf16_t;
typedef bf16_t bf16x8 __attribute__((ext_vector_type(8)));
typedef bf16_t bf16x4 __attribute__((ext_vector_type(4)));
typedef float f32x4 __attribute__((ext_vector_type(4)));

constexpr int DIM      = 128;
constexpr int FANOUT   = 5;
constexpr int NUM_EDGE = 20000;
constexpr int NUM_DST1 = 60000;    // (NEG+2)*NUM_EDGE
constexpr int NUM_DST0 = 360000;   // NUM_DST1*6

// ---------------------------------------------------------------------------
// Gather 0: hmean[d] = mean5(x[src0[d*5..]]) in bf16.
// One thread per (d, 16B-segment): 5 INDEPENDENT f32x4 loads per lane
// (explicit temporaries -> all 5 global_load_dwordx4 in flight, one waitcnt),
// 32 lanes per d -> each wave-instruction reads full 512B contiguous rows.
// Index loads are scalar (src + d*5 is only 4B-aligned; 32 lanes share d so
// they broadcast). Tiny VGPR footprint, max occupancy -> HBM-bound.
// ---------------------------------------------------------------------------
__global__ __launch_bounds__(256, 4) void k_gather0(
    const float* __restrict__ x, const int* __restrict__ src,
    unsigned short* __restrict__ out)
{
    const int t = blockIdx.x * 256 + threadIdx.x;
    const int d = t >> 5;
    if (d >= NUM_DST0) return;
    const int seg = (t & 31) * 4;           // float offset within row

    const int i0 = src[d * FANOUT + 0];
    const int i1 = src[d * FANOUT + 1];
    const int i2 = src[d * FANOUT + 2];
    const int i3 = src[d * FANOUT + 3];
    const int i4 = src[d * FANOUT + 4];

    f32x4 u0 = *(const f32x4*)(x + (long)i0 * DIM + seg);
    f32x4 u1 = *(const f32x4*)(x + (long)i1 * DIM + seg);
    f32x4 u2 = *(const f32x4*)(x + (long)i2 * DIM + seg);
    f32x4 u3 = *(const f32x4*)(x + (long)i3 * DIM + seg);
    f32x4 u4 = *(const f32x4*)(x + (long)i4 * DIM + seg);

    f32x4 a = (u0 + u1) + (u2 + u3) + u4;
    bf16x4 v;
#pragma unroll
    for (int j = 0; j < 4; ++j) v[j] = (bf16_t)(a[j] * 0.2f);
    *(bf16x4*)(out + (long)d * DIM + seg) = v;
}

// ---------------------------------------------------------------------------
// Gather 1: hmean1[d] = mean5(h[src1[d*5..]]) bf16 -> bf16 (L3-resident input).
// One thread per (d, 16B-segment of bf16 row): 5 independent bf16x8 loads.
// ---------------------------------------------------------------------------
__global__ __launch_bounds__(256, 4) void k_gather1(
    const unsigned short* __restrict__ h, const int* __restrict__ src,
    unsigned short* __restrict__ out)
{
    const int t = blockIdx.x * 256 + threadIdx.x;
    const int d = t >> 4;
    if (d >= NUM_DST1) return;
    const int seg = (t & 15) * 8;           // bf16 offset within row

    const int i0 = src[d * FANOUT + 0];
    const int i1 = src[d * FANOUT + 1];
    const int i2 = src[d * FANOUT + 2];
    const int i3 = src[d * FANOUT + 3];
    const int i4 = src[d * FANOUT + 4];

    bf16x8 u0 = *(const bf16x8*)(h + (long)i0 * DIM + seg);
    bf16x8 u1 = *(const bf16x8*)(h + (long)i1 * DIM + seg);
    bf16x8 u2 = *(const bf16x8*)(h + (long)i2 * DIM + seg);
    bf16x8 u3 = *(const bf16x8*)(h + (long)i3 * DIM + seg);
    bf16x8 u4 = *(const bf16x8*)(h + (long)i4 * DIM + seg);

    bf16x8 v;
#pragma unroll
    for (int j = 0; j < 8; ++j) {
        float a = (float)u0[j] + (float)u1[j] + (float)u2[j] +
                  (float)u3[j] + (float)u4[j];
        v[j] = (bf16_t)(a * 0.2f);
    }
    *(bf16x8*)(out + (long)d * DIM + seg) = v;
}

// ---------------------------------------------------------------------------
// Stage 1 GEMM (dense): h = relu(x[:360000] @ Wself0^T + hmean @ Wneigh0^T + b0)
// hmean/hout MAY ALIAS (in-place): each wave reads only its own 16 rows of
// hmean (values land in registers, consumed by MFMA) before storing those same
// 16 rows -> no restrict on the aliased pair, same-wave program order is safe.
// ---------------------------------------------------------------------------
__global__ __launch_bounds__(512, 4) void k_layer0_gemm(
    const float* __restrict__ x, const float* __restrict__ Wself,
    const float* __restrict__ Wneigh, const float* __restrict__ bias,
    const unsigned short* hmean, unsigned short* hout)
{
    __shared__ char smem[65536];
    const int tid = threadIdx.x;
    // stage Wcat[n][k] (n=0..127, k=0..255) as 32 chunks of 8 bf16 per row,
    // XOR-swizzled 16B chunks so B-frag ds_read_b128 is ~2-way (free).
    for (int idx = tid; idx < 128 * 32; idx += 512) {
        const int n = idx >> 5, c = idx & 31;
        const float* sp = (c < 16) ? (Wself + n * 128 + c * 8)
                                   : (Wneigh + n * 128 + (c - 16) * 8);
        bf16x8 v;
#pragma unroll
        for (int j = 0; j < 8; ++j) v[j] = (bf16_t)sp[j];
        *(bf16x8*)(smem + n * 512 + ((c ^ (n & 7)) << 4)) = v;
    }
    __syncthreads();

    const int lane = tid & 63;
    const int wv   = tid >> 6;
    const int n    = lane & 15;
    const int q    = lane >> 4;
    const int tile = blockIdx.x * 8 + wv;
    if (tile >= NUM_DST0 / 16) return;
    const int d = tile * 16 + n;

    bf16x8 afrag[8];                       // [0..3]=self, [4..7]=neigh mean
    const float* xrow = x + (long)d * DIM;
#pragma unroll
    for (int s = 0; s < 4; ++s) {
        const int k0 = s * 32 + q * 8;
        f32x4 u0 = *(const f32x4*)(xrow + k0);
        f32x4 u1 = *(const f32x4*)(xrow + k0 + 4);
        bf16x8 v;
#pragma unroll
        for (int j = 0; j < 4; ++j) { v[j] = (bf16_t)u0[j]; v[4 + j] = (bf16_t)u1[j]; }
        afrag[s] = v;
    }
#pragma unroll
    for (int s = 0; s < 4; ++s)
        afrag[4 + s] = *(const bf16x8*)(hmean + (long)d * DIM + s * 32 + q * 8);

    f32x4 acc[8];
#pragma unroll
    for (int t = 0; t < 8; ++t) acc[t] = (f32x4)(0.0f);
#pragma unroll
    for (int s = 0; s < 8; ++s) {
        const int c = 4 * s + q;           // k-chunk index 0..31
#pragma unroll
        for (int t = 0; t < 8; ++t) {
            const int row = 16 * t + n;
            bf16x8 bfrag = *(const bf16x8*)(smem + row * 512 + ((c ^ (row & 7)) << 4));
            acc[t] = __builtin_amdgcn_mfma_f32_16x16x32_bf16(afrag[s], bfrag, acc[t], 0, 0, 0);
        }
    }

    const long rowbase = (long)tile * 16 + q * 4;   // C-layout: row = quad*4+r
#pragma unroll
    for (int t = 0; t < 8; ++t) {
        const float bv = bias[16 * t + n];
#pragma unroll
        for (int r = 0; r < 4; ++r) {
            float v = acc[t][r] + bv;
            v = v > 0.f ? v : 0.f;
            hout[(rowbase + r) * DIM + 16 * t + n] =
                __builtin_bit_cast(unsigned short, (bf16_t)v);
        }
    }
}

// ---------------------------------------------------------------------------
// Stage 2 GEMM (dense): h1 = h[:60000] @ Wself1^T + hmean1 @ Wneigh1^T + b1
// hmean1/hout may alias (in-place), same argument as above. No relu.
// ---------------------------------------------------------------------------
__global__ __launch_bounds__(512, 4) void k_layer1_gemm(
    const unsigned short* __restrict__ h, const float* __restrict__ Wself,
    const float* __restrict__ Wneigh, const float* __restrict__ bias,
    const unsigned short* hmean, unsigned short* hout)
{
    __shared__ char smem[65536];
    const int tid = threadIdx.x;
    for (int idx = tid; idx < 128 * 32; idx += 512) {
        const int n = idx >> 5, c = idx & 31;
        const float* sp = (c < 16) ? (Wself + n * 128 + c * 8)
                                   : (Wneigh + n * 128 + (c - 16) * 8);
        bf16x8 v;
#pragma unroll
        for (int j = 0; j < 8; ++j) v[j] = (bf16_t)sp[j];
        *(bf16x8*)(smem + n * 512 + ((c ^ (n & 7)) << 4)) = v;
    }
    __syncthreads();

    const int lane = tid & 63;
    const int wv   = tid >> 6;
    const int n    = lane & 15;
    const int q    = lane >> 4;
    const int tile = blockIdx.x * 8 + wv;
    if (tile >= NUM_DST1 / 16) return;
    const int d = tile * 16 + n;

    bf16x8 afrag[8];
#pragma unroll
    for (int s = 0; s < 4; ++s)
        afrag[s] = *(const bf16x8*)(h + (long)d * DIM + s * 32 + q * 8);
#pragma unroll
    for (int s = 0; s < 4; ++s)
        afrag[4 + s] = *(const bf16x8*)(hmean + (long)d * DIM + s * 32 + q * 8);

    f32x4 acc[8];
#pragma unroll
    for (int t = 0; t < 8; ++t) acc[t] = (f32x4)(0.0f);
#pragma unroll
    for (int s = 0; s < 8; ++s) {
        const int c = 4 * s + q;
#pragma unroll
        for (int t = 0; t < 8; ++t) {
            const int row = 16 * t + n;
            bf16x8 bfrag = *(const bf16x8*)(smem + row * 512 + ((c ^ (row & 7)) << 4));
            acc[t] = __builtin_amdgcn_mfma_f32_16x16x32_bf16(afrag[s], bfrag, acc[t], 0, 0, 0);
        }
    }

    const long rowbase = (long)tile * 16 + q * 4;
#pragma unroll
    for (int t = 0; t < 8; ++t) {
        const float bv = bias[16 * t + n];
#pragma unroll
        for (int r = 0; r < 4; ++r) {
            float v = acc[t][r] + bv;   // no relu
            hout[(rowbase + r) * DIM + 16 * t + n] =
                __builtin_bit_cast(unsigned short, (bf16_t)v);
        }
    }
}

// ---------------------------------------------------------------------------
// Stage 3a: hmid = relu( (h1[r%20000] * h1[r+20000]) @ Wp1^T + bp1 ), r=0..40000
// ---------------------------------------------------------------------------
__global__ __launch_bounds__(256, 4) void k_pred1(
    const unsigned short* __restrict__ h1, const float* __restrict__ Wp1,
    const float* __restrict__ bp1, unsigned short* __restrict__ hmid)
{
    __shared__ char smem[32768];
    const int tid = threadIdx.x;
    for (int idx = tid; idx < 128 * 16; idx += 256) {
        const int n = idx >> 4, c = idx & 15;
        const float* sp = Wp1 + n * 128 + c * 8;
        bf16x8 v;
#pragma unroll
        for (int j = 0; j < 8; ++j) v[j] = (bf16_t)sp[j];
        *(bf16x8*)(smem + n * 256 + ((c ^ (n & 7)) << 4)) = v;
    }
    __syncthreads();

    const int lane = tid & 63;
    const int n    = lane & 15;
    const int q    = lane >> 4;
    const int tile = blockIdx.x * 4 + (tid >> 6);   // 2500 tiles exactly
    const int row  = tile * 16 + n;
    const int ra   = (row < NUM_EDGE) ? row : row - NUM_EDGE;
    const int rb   = row + NUM_EDGE;

    bf16x8 afrag[4];
#pragma unroll
    for (int s = 0; s < 4; ++s) {
        bf16x8 ua = *(const bf16x8*)(h1 + (long)ra * DIM + s * 32 + q * 8);
        bf16x8 ub = *(const bf16x8*)(h1 + (long)rb * DIM + s * 32 + q * 8);
        bf16x8 v;
#pragma unroll
        for (int j = 0; j < 8; ++j) v[j] = (bf16_t)((float)ua[j] * (float)ub[j]);
        afrag[s] = v;
    }

    f32x4 acc[8];
#pragma unroll
    for (int t = 0; t < 8; ++t) acc[t] = (f32x4)(0.0f);
#pragma unroll
    for (int s = 0; s < 4; ++s) {
        const int c = 4 * s + q;
#pragma unroll
        for (int t = 0; t < 8; ++t) {
            const int rw = 16 * t + n;
            bf16x8 bfrag = *(const bf16x8*)(smem + rw * 256 + ((c ^ (rw & 7)) << 4));
            acc[t] = __builtin_amdgcn_mfma_f32_16x16x32_bf16(afrag[s], bfrag, acc[t], 0, 0, 0);
        }
    }

    const long rowbase = (long)tile * 16 + q * 4;
#pragma unroll
    for (int t = 0; t < 8; ++t) {
        const float bv = bp1[16 * t + n];
#pragma unroll
        for (int r = 0; r < 4; ++r) {
            float v = acc[t][r] + bv;
            v = v > 0.f ? v : 0.f;
            hmid[(rowbase + r) * DIM + 16 * t + n] =
                __builtin_bit_cast(unsigned short, (bf16_t)v);
        }
    }
}

// ---------------------------------------------------------------------------
// Stage 3b: out = relu(hmid @ Wp2^T + bp2) @ Wp3^T + bp3  (fused P2+P3)
// ---------------------------------------------------------------------------
__global__ __launch_bounds__(256, 4) void k_pred2(
    const unsigned short* __restrict__ hmid, const float* __restrict__ Wp2,
    const float* __restrict__ bp2, const float* __restrict__ Wp3,
    const float* __restrict__ bp3, float* __restrict__ out)
{
    __shared__ char smem[32768];
    const int tid = threadIdx.x;
    for (int idx = tid; idx < 128 * 16; idx += 256) {
        const int n = idx >> 4, c = idx & 15;
        const float* sp = Wp2 + n * 128 + c * 8;
        bf16x8 v;
#pragma unroll
        for (int j = 0; j < 8; ++j) v[j] = (bf16_t)sp[j];
        *(bf16x8*)(smem + n * 256 + ((c ^ (n & 7)) << 4)) = v;
    }
    __syncthreads();

    const int lane = tid & 63;
    const int n    = lane & 15;
    const int q    = lane >> 4;
    const int tile = blockIdx.x * 4 + (tid >> 6);
    const int row  = tile * 16 + n;

    bf16x8 afrag[4];
#pragma unroll
    for (int s = 0; s < 4; ++s)
        afrag[s] = *(const bf16x8*)(hmid + (long)row * DIM + s * 32 + q * 8);

    f32x4 acc[8];
#pragma unroll
    for (int t = 0; t < 8; ++t) acc[t] = (f32x4)(0.0f);
#pragma unroll
    for (int s = 0; s < 4; ++s) {
        const int c = 4 * s + q;
#pragma unroll
        for (int t = 0; t < 8; ++t) {
            const int rw = 16 * t + n;
            bf16x8 bfrag = *(const bf16x8*)(smem + rw * 256 + ((c ^ (rw & 7)) << 4));
            acc[t] = __builtin_amdgcn_mfma_f32_16x16x32_bf16(afrag[s], bfrag, acc[t], 0, 0, 0);
        }
    }

    float osum[4] = {0.f, 0.f, 0.f, 0.f};
#pragma unroll
    for (int t = 0; t < 8; ++t) {
        const float b2 = bp2[16 * t + n];
        const float w3 = Wp3[16 * t + n];
#pragma unroll
        for (int r = 0; r < 4; ++r) {
            float v = acc[t][r] + b2;
            v = v > 0.f ? v : 0.f;
            osum[r] += v * w3;
        }
    }
    // reduce over the 16 column-lanes (n = lane&15)
#pragma unroll
    for (int m = 1; m <= 8; m <<= 1) {
#pragma unroll
        for (int r = 0; r < 4; ++r) osum[r] += __shfl_xor(osum[r], m, 64);
    }
    if (n == 0) {
        const float b3 = bp3[0];
#pragma unroll
        for (int r = 0; r < 4; ++r) out[tile * 16 + q * 4 + r] = osum[r] + b3;
    }
}

// ---------------------------------------------------------------------------
extern "C" void kernel_launch(void* const* d_in, const int* in_sizes, int n_in,
                              void* d_out, int out_size, void* d_ws, size_t ws_size,
                              hipStream_t stream) {
    const float* x       = (const float*)d_in[0];
    const float* Wself0  = (const float*)d_in[1];
    const float* Wneigh0 = (const float*)d_in[2];
    const float* b0      = (const float*)d_in[3];
    const float* Wself1  = (const float*)d_in[4];
    const float* Wneigh1 = (const float*)d_in[5];
    const float* b1      = (const float*)d_in[6];
    const float* Wp1     = (const float*)d_in[7];
    const float* bp1     = (const float*)d_in[8];
    const float* Wp2     = (const float*)d_in[9];
    const float* bp2     = (const float*)d_in[10];
    const float* Wp3     = (const float*)d_in[11];
    const float* bp3     = (const float*)d_in[12];
    const int*   src0    = (const int*)d_in[13];
    const int*   src1    = (const int*)d_in[15];
    // d_in[14]=dst0, d_in[16]=dst1 are repeat(arange,FANOUT): deg==5 exactly.

    // workspace: h bf16 (92.16MB), h1 bf16 (15.36MB); hmid reuses h's region.
    // Neighbor means are computed IN PLACE into h / h1 before the GEMMs
    // overwrite them row-by-row (each GEMM wave reads its own 16 rows into
    // registers before storing them) -> no extra workspace needed.
    unsigned short* h    = (unsigned short*)d_ws;
    unsigned short* h1   = h + (size_t)NUM_DST0 * DIM;
    unsigned short* hmid = (unsigned short*)d_ws;   // h is dead after layer1

    // Stage 1: gather-mean (BW-bound, high-MLP) then dense GEMM.
    k_gather0<<<dim3(NUM_DST0 * 32 / 256), dim3(256), 0, stream>>>(x, src0, h);
    k_layer0_gemm<<<dim3((NUM_DST0 / 16 + 7) / 8), dim3(512), 0, stream>>>(
        x, Wself0, Wneigh0, b0, h, h);
    // Stage 2: same split (input L3-resident).
    k_gather1<<<dim3(NUM_DST1 * 16 / 256), dim3(256), 0, stream>>>(h, src1, h1);
    k_layer1_gemm<<<dim3((NUM_DST1 / 16 + 7) / 8), dim3(512), 0, stream>>>(
        h, Wself1, Wneigh1, b1, h1, h1);
    k_pred1<<<dim3(625), dim3(256), 0, stream>>>(h1, Wp1, bp1, hmid);
    k_pred2<<<dim3(625), dim3(256), 0, stream>>>(hmid, Wp2, bp2, Wp3, bp3,
                                                 (float*)d_out);
}